// Round 1
// baseline (1264.215 us; speedup 1.0000x reference)
//
#include <hip/hip_runtime.h>
#include <math.h>

#define D_FEAT 1443
#define N0     100000
#define K1SEL  50000
#define K2SEL  25000
#define K3SEL  12500
#define NB1    2048      // level-1 histogram bins (key >> 21)
#define EQCAP  4096

// state layout (ints): [1]=thrKey [2]=need [3]=cntEq [4]=eqCount [5]=outCount
// [8..10]=invNorm(w1..w3) as float  [16..16+EQCAP)=eqbuf

__device__ __forceinline__ unsigned fkey(float f) {
    unsigned u = __float_as_uint(f);
    return (u & 0x80000000u) ? ~u : (u | 0x80000000u);
}

// zero level-1 histogram + d_out; compute 1/||w|| for all three w's (block 0)
__global__ __launch_bounds__(256) void init_kernel(
    const float* __restrict__ w1, const float* __restrict__ w2,
    const float* __restrict__ w3,
    unsigned* __restrict__ hist1, int* __restrict__ st,
    float* __restrict__ out, int outN)
{
    int gid = blockIdx.x * 256 + threadIdx.x;
    int gsz = gridDim.x * 256;
    for (int i = gid; i < NB1; i += gsz) hist1[i] = 0u;
    for (int i = gid; i < outN; i += gsz) out[i] = 0.0f;
    if (blockIdx.x == 0) {
        __shared__ double red[4];
        const float* ws_[3] = { w1, w2, w3 };
        for (int r = 0; r < 3; r++) {
            double nl = 0.0;
            for (int j = threadIdx.x; j < D_FEAT; j += 256) {
                double wv = (double)ws_[r][j]; nl += wv * wv;
            }
            for (int off = 32; off > 0; off >>= 1) nl += __shfl_down(nl, off);
            if ((threadIdx.x & 63) == 0) red[threadIdx.x >> 6] = nl;
            __syncthreads();
            if (threadIdx.x == 0)
                ((float*)st)[8 + r] = (float)(1.0 / sqrt(red[0] + red[1] + red[2] + red[3]));
            __syncthreads();
        }
        if (threadIdx.x < 8) st[threadIdx.x] = 0;
    }
}

// one wave per row: d2=x@w2, d3=x@w3; round-1 score/key/hist fused (d1 never stored)
__global__ __launch_bounds__(256) void dots_kernel(
    const float* __restrict__ x,
    const float* __restrict__ w1, const float* __restrict__ w2,
    const float* __restrict__ w3,
    float* __restrict__ d2, float* __restrict__ d3,
    unsigned* __restrict__ keys, float* __restrict__ sv,
    unsigned* __restrict__ hist1, const int* __restrict__ st)
{
    int wave = threadIdx.x >> 6, lane = threadIdx.x & 63;
    int row = blockIdx.x * 4 + wave;
    if (row >= N0) return;
    const float* xr = x + (long)row * D_FEAT;
    double a1 = 0.0, a2 = 0.0, a3 = 0.0;
    for (int j = lane; j < D_FEAT; j += 64) {
        double xv = (double)xr[j];
        a1 += xv * (double)w1[j];
        a2 += xv * (double)w2[j];
        a3 += xv * (double)w3[j];
    }
    for (int off = 32; off > 0; off >>= 1) {
        a1 += __shfl_down(a1, off);
        a2 += __shfl_down(a2, off);
        a3 += __shfl_down(a3, off);
    }
    if (lane == 0) {
        d2[row] = (float)a2;
        d3[row] = (float)a3;
        float invN = ((const float*)st)[8];
        float s = tanhf((float)a1 * invN);
        sv[row] = s;
        unsigned key = fkey(s);
        keys[row] = key;
        atomicAdd(&hist1[key >> 21], 1u);
    }
}

// suffix-pick over a 2048-bin LDS histogram. 1024 threads, 2 bins each.
// finds bin b with suffix(b) >= kRem > suffix(b+1); writes sel/need/hsel (shared).
__device__ __forceinline__ void pick2048(
    unsigned* h, unsigned* scan, unsigned kRem,
    unsigned* selS, unsigned* needS, unsigned* hselS)
{
    int tid = threadIdx.x;
    unsigned h0 = h[2 * tid], h1 = h[2 * tid + 1];
    scan[tid] = h0 + h1;
    __syncthreads();
    for (int off = 1; off < 1024; off <<= 1) {
        unsigned v = scan[tid] + ((tid + off < 1024) ? scan[tid + off] : 0u);
        __syncthreads();
        scan[tid] = v;
        __syncthreads();
    }
    unsigned S  = scan[tid];                         // suffix at bin 2t
    unsigned Sn = (tid < 1023) ? scan[tid + 1] : 0u; // suffix at bin 2t+2
    unsigned sufB = S - h0;                          // suffix at bin 2t+1
    if (S >= kRem && sufB < kRem)  { *selS = 2u * tid;     *needS = kRem - sufB; *hselS = h0; }
    if (sufB >= kRem && Sn < kRem) { *selS = 2u * tid + 1; *needS = kRem - Sn;   *hselS = h1; }
    __syncthreads();
}

// single block: full 3-level (11/11/10-bit) radix select in LDS.
// consumes global hist1 (level 1) and zeroes it for the next round.
// emits st[1]=exact 32-bit threshold key, st[2]=need among equals, st[4]=st[5]=0.
__global__ __launch_bounds__(1024) void fpick_kernel(
    const unsigned* __restrict__ keys, int n,
    unsigned* __restrict__ hist1, int* __restrict__ st, int k0)
{
    __shared__ unsigned h[NB1];
    __shared__ unsigned scan[1024];
    __shared__ unsigned selS, needS, hselS;
    int tid = threadIdx.x;

    // ---- level 1: global hist -> LDS; zero global for next round's atomics
    h[2 * tid]     = hist1[2 * tid];
    h[2 * tid + 1] = hist1[2 * tid + 1];
    hist1[2 * tid] = 0u; hist1[2 * tid + 1] = 0u;
    __syncthreads();
    pick2048(h, scan, (unsigned)k0, &selS, &needS, &hselS);
    unsigned s1 = selS, kRem2 = needS;
    __syncthreads();

    // ---- level 2: histogram (key>>10)&0x7FF for keys in level-1 bin
    h[2 * tid] = 0u; h[2 * tid + 1] = 0u;
    __syncthreads();
    for (int i = tid; i < n; i += 1024) {
        unsigned k = keys[i];
        if ((k >> 21) == s1) atomicAdd(&h[(k >> 10) & 0x7FFu], 1u);
    }
    __syncthreads();
    pick2048(h, scan, kRem2, &selS, &needS, &hselS);
    unsigned s2 = selS, kRem3 = needS;
    unsigned pref = (s1 << 11) | s2;   // == key >> 10 of the threshold
    __syncthreads();

    // ---- level 3: histogram key&0x3FF (1024 bins; upper half stays zero)
    h[2 * tid] = 0u; h[2 * tid + 1] = 0u;
    __syncthreads();
    for (int i = tid; i < n; i += 1024) {
        unsigned k = keys[i];
        if ((k >> 10) == pref) atomicAdd(&h[k & 0x3FFu], 1u);
    }
    __syncthreads();
    pick2048(h, scan, kRem3, &selS, &needS, &hselS);
    if (tid == 0) {
        st[1] = (int)((s1 << 21) | (s2 << 10) | selS);
        st[2] = (int)needS;
        st[3] = (int)hselS;
        st[4] = 0;
        st[5] = 0;
    }
}

// compact survivors (key > thr); record boundary ties; FUSED: compute next-round
// score/key/hist for each survivor as it is written (dNext==null on last round).
__global__ __launch_bounds__(256) void compact_kernel(
    const unsigned* __restrict__ keysIn, const float* __restrict__ svIn,
    const int* __restrict__ idxIn, const float* __restrict__ cumIn, int n,
    int* __restrict__ idxOut, float* __restrict__ cumOut,
    int* __restrict__ st,
    const float* __restrict__ dNext, unsigned* __restrict__ keysOut,
    float* __restrict__ svOut, unsigned* __restrict__ hist1, int wIdx)
{
    int gid = blockIdx.x * 256 + threadIdx.x;
    if (gid >= n) return;
    unsigned thr = (unsigned)st[1];
    unsigned key = keysIn[gid];
    if (key > thr) {
        int pos = atomicAdd(&st[5], 1);
        int row = idxIn ? idxIn[gid] : gid;
        float c = (idxIn ? cumIn[gid] : 1.0f) * svIn[gid];
        idxOut[pos] = row;
        cumOut[pos] = c;
        if (dNext) {
            float invN = ((const float*)st)[8 + wIdx];
            float s = tanhf(c * dNext[row] * invN);
            svOut[pos] = s;
            unsigned k2 = fkey(s);
            keysOut[pos] = k2;
            atomicAdd(&hist1[k2 >> 21], 1u);
        }
    } else if (key == thr) {
        int e = atomicAdd(&st[4], 1);
        if (e < EQCAP) st[16 + e] = gid;
    }
}

// boundary ties: take `need` lowest positions among key == thr; FUSED next-score.
__global__ __launch_bounds__(256) void tie_kernel(
    const float* __restrict__ svIn, const int* __restrict__ idxIn,
    const float* __restrict__ cumIn, int k,
    int* __restrict__ idxOut, float* __restrict__ cumOut, int* __restrict__ st,
    const float* __restrict__ dNext, unsigned* __restrict__ keysOut,
    float* __restrict__ svOut, unsigned* __restrict__ hist1, int wIdx)
{
    int cnt = st[4]; if (cnt > EQCAP) cnt = EQCAP;
    int need = st[2];
    int base = k - need;
    for (int e = threadIdx.x; e < cnt; e += 256) {
        int pos = st[16 + e];
        int rank = 0;
        for (int e2 = 0; e2 < cnt; e2++) rank += (st[16 + e2] < pos) ? 1 : 0;
        if (rank < need) {
            int row = idxIn ? idxIn[pos] : pos;
            float c = (idxIn ? cumIn[pos] : 1.0f) * svIn[pos];
            idxOut[base + rank] = row;
            cumOut[base + rank] = c;
            if (dNext) {
                float invN = ((const float*)st)[8 + wIdx];
                float s = tanhf(c * dNext[row] * invN);
                svOut[base + rank] = s;
                unsigned k2 = fkey(s);
                keysOut[base + rank] = k2;
                atomicAdd(&hist1[k2 >> 21], 1u);
            }
        }
    }
}

#define WS_ROWS 64
// out[c] += (1/K3SEL) * sum_r cum3[r] * x[idx3[r]][c]
__global__ __launch_bounds__(256) void wsum_kernel(
    const float* __restrict__ x, const int* __restrict__ idx3,
    const float* __restrict__ cum3, float* __restrict__ out)
{
    int col = blockIdx.x * 256 + threadIdx.x;
    int r0 = blockIdx.y * WS_ROWS;
    int r1 = r0 + WS_ROWS; if (r1 > K3SEL) r1 = K3SEL;
    float acc = 0.0f;
    for (int r = r0; r < r1; r++) {
        int row = idx3[r];
        float wgt = cum3[r];
        if (col < D_FEAT) acc += wgt * x[(long)row * D_FEAT + col];
    }
    if (col < D_FEAT) atomicAdd(&out[col], acc * (1.0f / (float)K3SEL));
}

extern "C" void kernel_launch(void* const* d_in, const int* in_sizes, int n_in,
                              void* d_out, int out_size, void* d_ws, size_t ws_size,
                              hipStream_t stream) {
    const float* x  = (const float*)d_in[0];
    const float* w1 = (const float*)d_in[3];
    const float* w2 = (const float*)d_in[4];
    const float* w3 = (const float*)d_in[5];
    float* out = (float*)d_out;

    float* ws = (float*)d_ws;
    float*    d2    = ws;                          // 100000
    float*    d3    = ws + 100000;                 // 100000
    unsigned* keysA = (unsigned*)(ws + 200000);    // 100000
    float*    svA   = ws + 300000;                 // 100000
    int*      idx1  = (int*)(ws + 400000);         // 50000
    float*    cum1  = ws + 450000;                 // 50000
    unsigned* keysB = (unsigned*)(ws + 500000);    // 50000
    float*    svB   = ws + 550000;                 // 50000
    int*      idx2  = (int*)(ws + 600000);         // 25000
    float*    cum2  = ws + 625000;                 // 25000
    unsigned* keysC = (unsigned*)(ws + 650000);    // 25000
    float*    svC   = ws + 675000;                 // 25000
    int*      idx3  = (int*)(ws + 700000);         // 12500
    float*    cum3  = ws + 712500;                 // 12500
    unsigned* hist1 = (unsigned*)(ws + 725000);    // 2048
    int*      st    = (int*)(ws + 725000 + NB1);   // 16 + EQCAP

    init_kernel<<<dim3(16), dim3(256), 0, stream>>>(w1, w2, w3, hist1, st, out, out_size);

    dots_kernel<<<dim3(N0 / 4), dim3(256), 0, stream>>>(x, w1, w2, w3, d2, d3,
                                                        keysA, svA, hist1, st);

    // ---- round 1: n=100000 -> k=50000 (compact also scores round 2 with d2)
    fpick_kernel<<<1, 1024, 0, stream>>>(keysA, N0, hist1, st, K1SEL);
    compact_kernel<<<dim3((N0 + 255) / 256), dim3(256), 0, stream>>>(
        keysA, svA, nullptr, nullptr, N0, idx1, cum1, st,
        d2, keysB, svB, hist1, 1);
    tie_kernel<<<1, 256, 0, stream>>>(svA, nullptr, nullptr, K1SEL, idx1, cum1, st,
                                      d2, keysB, svB, hist1, 1);

    // ---- round 2: n=50000 -> k=25000 (compact also scores round 3 with d3)
    fpick_kernel<<<1, 1024, 0, stream>>>(keysB, K1SEL, hist1, st, K2SEL);
    compact_kernel<<<dim3((K1SEL + 255) / 256), dim3(256), 0, stream>>>(
        keysB, svB, idx1, cum1, K1SEL, idx2, cum2, st,
        d3, keysC, svC, hist1, 2);
    tie_kernel<<<1, 256, 0, stream>>>(svB, idx1, cum1, K2SEL, idx2, cum2, st,
                                      d3, keysC, svC, hist1, 2);

    // ---- round 3: n=25000 -> k=12500 (no next round)
    fpick_kernel<<<1, 1024, 0, stream>>>(keysC, K2SEL, hist1, st, K3SEL);
    compact_kernel<<<dim3((K2SEL + 255) / 256), dim3(256), 0, stream>>>(
        keysC, svC, idx2, cum2, K2SEL, idx3, cum3, st,
        nullptr, nullptr, nullptr, nullptr, 0);
    tie_kernel<<<1, 256, 0, stream>>>(svC, idx2, cum2, K3SEL, idx3, cum3, st,
                                      nullptr, nullptr, nullptr, nullptr, 0);

    // ---- final mean over 12500 weighted rows
    wsum_kernel<<<dim3((D_FEAT + 255) / 256, (K3SEL + WS_ROWS - 1) / WS_ROWS),
                  dim3(256), 0, stream>>>(x, idx3, cum3, out);
}

// Round 2
// 983.611 us; speedup vs baseline: 1.2853x; 1.2853x over previous
//
#include <hip/hip_runtime.h>
#include <math.h>

#define D_FEAT 1443
#define N0     100000
#define K1SEL  50000
#define K2SEL  25000
#define K3SEL  12500
#define NB1    2048      // radix bins per level (11/11/10 bits)
#define EQCAP  4096

// state layout (ints): [1]=thrKey [2]=need [3]=cntEq [4]=eqCount [5]=outCount
// [8..10]=invNorm(w1..w3) as float  [16..16+EQCAP)=eqbuf

__device__ __forceinline__ unsigned fkey(float f) {
    unsigned u = __float_as_uint(f);
    return (u & 0x80000000u) ? ~u : (u | 0x80000000u);
}

// zero d_out; compute 1/||w|| for all three w's (block 0)
__global__ __launch_bounds__(256) void init_kernel(
    const float* __restrict__ w1, const float* __restrict__ w2,
    const float* __restrict__ w3,
    int* __restrict__ st, float* __restrict__ out, int outN)
{
    int gid = blockIdx.x * 256 + threadIdx.x;
    int gsz = gridDim.x * 256;
    for (int i = gid; i < outN; i += gsz) out[i] = 0.0f;
    if (blockIdx.x == 0) {
        __shared__ double red[4];
        const float* ws_[3] = { w1, w2, w3 };
        for (int r = 0; r < 3; r++) {
            double nl = 0.0;
            for (int j = threadIdx.x; j < D_FEAT; j += 256) {
                double wv = (double)ws_[r][j]; nl += wv * wv;
            }
            for (int off = 32; off > 0; off >>= 1) nl += __shfl_down(nl, off);
            if ((threadIdx.x & 63) == 0) red[threadIdx.x >> 6] = nl;
            __syncthreads();
            if (threadIdx.x == 0)
                ((float*)st)[8 + r] = (float)(1.0 / sqrt(red[0] + red[1] + red[2] + red[3]));
            __syncthreads();
        }
        if (threadIdx.x < 8) st[threadIdx.x] = 0;
    }
}

// one wave per row, float4-vectorized: d2=x@w2, d3=x@w3; round-1 score/key fused.
// 360 float4 = elements 0..1439; 3-element scalar tail. No histogram atomics.
__global__ __launch_bounds__(256) void dots_kernel(
    const float* __restrict__ x,
    const float* __restrict__ w1, const float* __restrict__ w2,
    const float* __restrict__ w3,
    float* __restrict__ d2, float* __restrict__ d3,
    unsigned* __restrict__ keys, float* __restrict__ sv,
    const int* __restrict__ st)
{
    int wave = threadIdx.x >> 6, lane = threadIdx.x & 63;
    int row = blockIdx.x * 4 + wave;
    if (row >= N0) return;
    const float* xr = x + (long)row * D_FEAT;
    const float4* xr4 = (const float4*)xr;
    const float4* W1 = (const float4*)w1;
    const float4* W2 = (const float4*)w2;
    const float4* W3 = (const float4*)w3;
    double a1 = 0.0, a2 = 0.0, a3 = 0.0;
    #pragma unroll
    for (int it = 0; it < 5; it++) {
        int j4 = lane + it * 64;
        float4 xv = xr4[j4];
        float4 v1 = W1[j4], v2 = W2[j4], v3 = W3[j4];
        a1 += (double)xv.x * (double)v1.x; a2 += (double)xv.x * (double)v2.x; a3 += (double)xv.x * (double)v3.x;
        a1 += (double)xv.y * (double)v1.y; a2 += (double)xv.y * (double)v2.y; a3 += (double)xv.y * (double)v3.y;
        a1 += (double)xv.z * (double)v1.z; a2 += (double)xv.z * (double)v2.z; a3 += (double)xv.z * (double)v3.z;
        a1 += (double)xv.w * (double)v1.w; a2 += (double)xv.w * (double)v2.w; a3 += (double)xv.w * (double)v3.w;
    }
    if (lane < 40) {
        int j4 = lane + 320;
        float4 xv = xr4[j4];
        float4 v1 = W1[j4], v2 = W2[j4], v3 = W3[j4];
        a1 += (double)xv.x * (double)v1.x; a2 += (double)xv.x * (double)v2.x; a3 += (double)xv.x * (double)v3.x;
        a1 += (double)xv.y * (double)v1.y; a2 += (double)xv.y * (double)v2.y; a3 += (double)xv.y * (double)v3.y;
        a1 += (double)xv.z * (double)v1.z; a2 += (double)xv.z * (double)v2.z; a3 += (double)xv.z * (double)v3.z;
        a1 += (double)xv.w * (double)v1.w; a2 += (double)xv.w * (double)v2.w; a3 += (double)xv.w * (double)v3.w;
    }
    if (lane < 3) {
        int j = 1440 + lane;
        double xv = (double)xr[j];
        a1 += xv * (double)w1[j];
        a2 += xv * (double)w2[j];
        a3 += xv * (double)w3[j];
    }
    for (int off = 32; off > 0; off >>= 1) {
        a1 += __shfl_down(a1, off);
        a2 += __shfl_down(a2, off);
        a3 += __shfl_down(a3, off);
    }
    if (lane == 0) {
        d2[row] = (float)a2;
        d3[row] = (float)a3;
        float invN = ((const float*)st)[8];
        float s = tanhf((float)a1 * invN);
        sv[row] = s;
        keys[row] = fkey(s);
    }
}

// suffix-pick over a 2048-bin LDS histogram. 1024 threads, 2 bins each.
__device__ __forceinline__ void pick2048(
    unsigned* h, unsigned* scan, unsigned kRem,
    unsigned* selS, unsigned* needS, unsigned* hselS)
{
    int tid = threadIdx.x;
    unsigned h0 = h[2 * tid], h1 = h[2 * tid + 1];
    scan[tid] = h0 + h1;
    __syncthreads();
    for (int off = 1; off < 1024; off <<= 1) {
        unsigned v = scan[tid] + ((tid + off < 1024) ? scan[tid + off] : 0u);
        __syncthreads();
        scan[tid] = v;
        __syncthreads();
    }
    unsigned S  = scan[tid];                         // suffix at bin 2t
    unsigned Sn = (tid < 1023) ? scan[tid + 1] : 0u; // suffix at bin 2t+2
    unsigned sufB = S - h0;                          // suffix at bin 2t+1
    if (S >= kRem && sufB < kRem)  { *selS = 2u * tid;     *needS = kRem - sufB; *hselS = h0; }
    if (sufB >= kRem && Sn < kRem) { *selS = 2u * tid + 1; *needS = kRem - Sn;   *hselS = h1; }
    __syncthreads();
}

// single block: full 3-level (11/11/10-bit) radix select, all levels built here.
// level 1 uses 8 per-wave-group sub-hists to avoid hot-bin LDS serialization
// (tanh-compressed scores put ~9% of keys into one 11-bit bin).
__global__ __launch_bounds__(1024) void fpick_kernel(
    const unsigned* __restrict__ keys, int n, int* __restrict__ st, int k0)
{
    __shared__ unsigned h8[8][NB1];     // 64 KB
    __shared__ unsigned scan[1024];
    __shared__ unsigned selS, needS, hselS;
    int tid = threadIdx.x;
    int sub = (tid >> 6) & 7;
    unsigned* h = h8[0];

    // ---- level 1: build from keys
    for (int i = tid; i < 8 * NB1; i += 1024) ((unsigned*)h8)[i] = 0u;
    __syncthreads();
    for (int i = tid; i < n; i += 1024)
        atomicAdd(&h8[sub][keys[i] >> 21], 1u);
    __syncthreads();
    for (int b = tid; b < NB1; b += 1024) {
        unsigned s = h8[0][b];
        for (int w = 1; w < 8; w++) s += h8[w][b];
        h[b] = s;
    }
    __syncthreads();
    pick2048(h, scan, (unsigned)k0, &selS, &needS, &hselS);
    unsigned s1 = selS, kRem2 = needS;
    __syncthreads();

    // ---- level 2: histogram (key>>10)&0x7FF for keys in level-1 bin
    for (int b = tid; b < NB1; b += 1024) h[b] = 0u;
    __syncthreads();
    for (int i = tid; i < n; i += 1024) {
        unsigned k = keys[i];
        if ((k >> 21) == s1) atomicAdd(&h[(k >> 10) & 0x7FFu], 1u);
    }
    __syncthreads();
    pick2048(h, scan, kRem2, &selS, &needS, &hselS);
    unsigned s2 = selS, kRem3 = needS;
    unsigned pref = (s1 << 11) | s2;   // == key >> 10 of the threshold
    __syncthreads();

    // ---- level 3: histogram key&0x3FF (1024 bins; upper half stays zero)
    for (int b = tid; b < NB1; b += 1024) h[b] = 0u;
    __syncthreads();
    for (int i = tid; i < n; i += 1024) {
        unsigned k = keys[i];
        if ((k >> 10) == pref) atomicAdd(&h[k & 0x3FFu], 1u);
    }
    __syncthreads();
    pick2048(h, scan, kRem3, &selS, &needS, &hselS);
    if (tid == 0) {
        st[1] = (int)((s1 << 21) | (s2 << 10) | selS);
        st[2] = (int)needS;
        st[3] = (int)hselS;
        st[4] = 0;
        st[5] = 0;
    }
}

// compact survivors (key > thr); record boundary ties; FUSED: compute next-round
// score/key for each survivor as it is written (dNext==null on last round).
__global__ __launch_bounds__(256) void compact_kernel(
    const unsigned* __restrict__ keysIn, const float* __restrict__ svIn,
    const int* __restrict__ idxIn, const float* __restrict__ cumIn, int n,
    int* __restrict__ idxOut, float* __restrict__ cumOut,
    int* __restrict__ st,
    const float* __restrict__ dNext, unsigned* __restrict__ keysOut,
    float* __restrict__ svOut, int wIdx)
{
    int gid = blockIdx.x * 256 + threadIdx.x;
    if (gid >= n) return;
    unsigned thr = (unsigned)st[1];
    unsigned key = keysIn[gid];
    if (key > thr) {
        int pos = atomicAdd(&st[5], 1);
        int row = idxIn ? idxIn[gid] : gid;
        float c = (idxIn ? cumIn[gid] : 1.0f) * svIn[gid];
        idxOut[pos] = row;
        cumOut[pos] = c;
        if (dNext) {
            float invN = ((const float*)st)[8 + wIdx];
            float s = tanhf(c * dNext[row] * invN);
            svOut[pos] = s;
            keysOut[pos] = fkey(s);
        }
    } else if (key == thr) {
        int e = atomicAdd(&st[4], 1);
        if (e < EQCAP) st[16 + e] = gid;
    }
}

// boundary ties: take `need` lowest positions among key == thr; FUSED next-score.
__global__ __launch_bounds__(256) void tie_kernel(
    const float* __restrict__ svIn, const int* __restrict__ idxIn,
    const float* __restrict__ cumIn, int k,
    int* __restrict__ idxOut, float* __restrict__ cumOut, int* __restrict__ st,
    const float* __restrict__ dNext, unsigned* __restrict__ keysOut,
    float* __restrict__ svOut, int wIdx)
{
    int cnt = st[4]; if (cnt > EQCAP) cnt = EQCAP;
    int need = st[2];
    int base = k - need;
    for (int e = threadIdx.x; e < cnt; e += 256) {
        int pos = st[16 + e];
        int rank = 0;
        for (int e2 = 0; e2 < cnt; e2++) rank += (st[16 + e2] < pos) ? 1 : 0;
        if (rank < need) {
            int row = idxIn ? idxIn[pos] : pos;
            float c = (idxIn ? cumIn[pos] : 1.0f) * svIn[pos];
            idxOut[base + rank] = row;
            cumOut[base + rank] = c;
            if (dNext) {
                float invN = ((const float*)st)[8 + wIdx];
                float s = tanhf(c * dNext[row] * invN);
                svOut[base + rank] = s;
                keysOut[base + rank] = fkey(s);
            }
        }
    }
}

#define WS_ROWS 64
// out[c] += (1/K3SEL) * sum_r cum3[r] * x[idx3[r]][c]
__global__ __launch_bounds__(256) void wsum_kernel(
    const float* __restrict__ x, const int* __restrict__ idx3,
    const float* __restrict__ cum3, float* __restrict__ out)
{
    int col = blockIdx.x * 256 + threadIdx.x;
    int r0 = blockIdx.y * WS_ROWS;
    int r1 = r0 + WS_ROWS; if (r1 > K3SEL) r1 = K3SEL;
    float acc = 0.0f;
    for (int r = r0; r < r1; r++) {
        int row = idx3[r];
        float wgt = cum3[r];
        if (col < D_FEAT) acc += wgt * x[(long)row * D_FEAT + col];
    }
    if (col < D_FEAT) atomicAdd(&out[col], acc * (1.0f / (float)K3SEL));
}

extern "C" void kernel_launch(void* const* d_in, const int* in_sizes, int n_in,
                              void* d_out, int out_size, void* d_ws, size_t ws_size,
                              hipStream_t stream) {
    const float* x  = (const float*)d_in[0];
    const float* w1 = (const float*)d_in[3];
    const float* w2 = (const float*)d_in[4];
    const float* w3 = (const float*)d_in[5];
    float* out = (float*)d_out;

    float* ws = (float*)d_ws;
    float*    d2    = ws;                          // 100000
    float*    d3    = ws + 100000;                 // 100000
    unsigned* keysA = (unsigned*)(ws + 200000);    // 100000
    float*    svA   = ws + 300000;                 // 100000
    int*      idx1  = (int*)(ws + 400000);         // 50000
    float*    cum1  = ws + 450000;                 // 50000
    unsigned* keysB = (unsigned*)(ws + 500000);    // 50000
    float*    svB   = ws + 550000;                 // 50000
    int*      idx2  = (int*)(ws + 600000);         // 25000
    float*    cum2  = ws + 625000;                 // 25000
    unsigned* keysC = (unsigned*)(ws + 650000);    // 25000
    float*    svC   = ws + 675000;                 // 25000
    int*      idx3  = (int*)(ws + 700000);         // 12500
    float*    cum3  = ws + 712500;                 // 12500
    int*      st    = (int*)(ws + 725000);         // 16 + EQCAP

    init_kernel<<<dim3(16), dim3(256), 0, stream>>>(w1, w2, w3, st, out, out_size);

    dots_kernel<<<dim3(N0 / 4), dim3(256), 0, stream>>>(x, w1, w2, w3, d2, d3,
                                                        keysA, svA, st);

    // ---- round 1: n=100000 -> k=50000 (compact also scores round 2 with d2)
    fpick_kernel<<<1, 1024, 0, stream>>>(keysA, N0, st, K1SEL);
    compact_kernel<<<dim3((N0 + 255) / 256), dim3(256), 0, stream>>>(
        keysA, svA, nullptr, nullptr, N0, idx1, cum1, st, d2, keysB, svB, 1);
    tie_kernel<<<1, 256, 0, stream>>>(svA, nullptr, nullptr, K1SEL, idx1, cum1, st,
                                      d2, keysB, svB, 1);

    // ---- round 2: n=50000 -> k=25000 (compact also scores round 3 with d3)
    fpick_kernel<<<1, 1024, 0, stream>>>(keysB, K1SEL, st, K2SEL);
    compact_kernel<<<dim3((K1SEL + 255) / 256), dim3(256), 0, stream>>>(
        keysB, svB, idx1, cum1, K1SEL, idx2, cum2, st, d3, keysC, svC, 2);
    tie_kernel<<<1, 256, 0, stream>>>(svB, idx1, cum1, K2SEL, idx2, cum2, st,
                                      d3, keysC, svC, 2);

    // ---- round 3: n=25000 -> k=12500 (no next round)
    fpick_kernel<<<1, 1024, 0, stream>>>(keysC, K2SEL, st, K3SEL);
    compact_kernel<<<dim3((K2SEL + 255) / 256), dim3(256), 0, stream>>>(
        keysC, svC, idx2, cum2, K2SEL, idx3, cum3, st, nullptr, nullptr, nullptr, 0);
    tie_kernel<<<1, 256, 0, stream>>>(svC, idx2, cum2, K3SEL, idx3, cum3, st,
                                      nullptr, nullptr, nullptr, 0);

    // ---- final mean over 12500 weighted rows
    wsum_kernel<<<dim3((D_FEAT + 255) / 256, (K3SEL + WS_ROWS - 1) / WS_ROWS),
                  dim3(256), 0, stream>>>(x, idx3, cum3, out);
}

// Round 3
// 965.173 us; speedup vs baseline: 1.3098x; 1.0191x over previous
//
#include <hip/hip_runtime.h>
#include <math.h>

#define D_FEAT 1443
#define N0     100000
#define K1SEL  50000
#define K2SEL  25000
#define K3SEL  12500
#define NB1    2048      // radix bins per level (11/11/10 bits)
#define EQCAP  4096
#define WSTRIDE 1444     // per-array float stride in LDS (16B-aligned)

// state layout (ints): [1]=thrKey [2]=need [3]=hsel [4]=eqCount [5]=outCount
// [8..10]=invNorm(w1..w3) as float  [16..16+EQCAP)=eqbuf

__device__ __forceinline__ unsigned fkey(float f) {
    unsigned u = __float_as_uint(f);
    return (u & 0x80000000u) ? ~u : (u | 0x80000000u);
}

// zero d_out; compute 1/||w|| for all three w's (block 0)
__global__ __launch_bounds__(256) void init_kernel(
    const float* __restrict__ w1, const float* __restrict__ w2,
    const float* __restrict__ w3,
    int* __restrict__ st, float* __restrict__ out, int outN)
{
    int gid = blockIdx.x * 256 + threadIdx.x;
    int gsz = gridDim.x * 256;
    for (int i = gid; i < outN; i += gsz) out[i] = 0.0f;
    if (blockIdx.x == 0) {
        __shared__ double red[4];
        const float* ws_[3] = { w1, w2, w3 };
        for (int r = 0; r < 3; r++) {
            double nl = 0.0;
            for (int j = threadIdx.x; j < D_FEAT; j += 256) {
                double wv = (double)ws_[r][j]; nl += wv * wv;
            }
            for (int off = 32; off > 0; off >>= 1) nl += __shfl_down(nl, off);
            if ((threadIdx.x & 63) == 0) red[threadIdx.x >> 6] = nl;
            __syncthreads();
            if (threadIdx.x == 0)
                ((float*)st)[8 + r] = (float)(1.0 / sqrt(red[0] + red[1] + red[2] + red[3]));
            __syncthreads();
        }
        if (threadIdx.x < 8) st[threadIdx.x] = 0;
    }
}

// one wave per row, float4 x from HBM, w1/w2/w3 staged in LDS (ds_read pipe).
// 16 rows per 1024-thread block; round-1 score/key fused (d1 never stored).
// Per-lane arithmetic order identical to the verified scalar/float4 version.
__global__ __launch_bounds__(1024) void dots_kernel(
    const float* __restrict__ x,
    const float* __restrict__ w1, const float* __restrict__ w2,
    const float* __restrict__ w3,
    float* __restrict__ d2, float* __restrict__ d3,
    unsigned* __restrict__ keys, float* __restrict__ sv,
    const int* __restrict__ st)
{
    __shared__ float wsh[3 * WSTRIDE];
    int tid = threadIdx.x;
    {
        const float* ws_[3] = { w1, w2, w3 };
        #pragma unroll
        for (int r = 0; r < 3; r++) {
            float4* dst = (float4*)(wsh + r * WSTRIDE);
            const float4* src = (const float4*)ws_[r];
            for (int i = tid; i < 360; i += 1024) dst[i] = src[i];
        }
        if (tid < 9) {
            int r = tid / 3, t = tid - r * 3;
            wsh[r * WSTRIDE + 1440 + t] = ws_[r][1440 + t];
        }
    }
    __syncthreads();

    int wave = tid >> 6, lane = tid & 63;
    int row = blockIdx.x * 16 + wave;
    if (row >= N0) return;
    const float* xr = x + (long)row * D_FEAT;
    const float4* xr4 = (const float4*)xr;
    const float4* W1 = (const float4*)(wsh);
    const float4* W2 = (const float4*)(wsh + WSTRIDE);
    const float4* W3 = (const float4*)(wsh + 2 * WSTRIDE);
    double a1 = 0.0, a2 = 0.0, a3 = 0.0;
    #pragma unroll
    for (int it = 0; it < 5; it++) {
        int j4 = lane + it * 64;
        float4 xv = xr4[j4];
        float4 v1 = W1[j4], v2 = W2[j4], v3 = W3[j4];
        a1 += (double)xv.x * (double)v1.x; a2 += (double)xv.x * (double)v2.x; a3 += (double)xv.x * (double)v3.x;
        a1 += (double)xv.y * (double)v1.y; a2 += (double)xv.y * (double)v2.y; a3 += (double)xv.y * (double)v3.y;
        a1 += (double)xv.z * (double)v1.z; a2 += (double)xv.z * (double)v2.z; a3 += (double)xv.z * (double)v3.z;
        a1 += (double)xv.w * (double)v1.w; a2 += (double)xv.w * (double)v2.w; a3 += (double)xv.w * (double)v3.w;
    }
    if (lane < 40) {
        int j4 = lane + 320;
        float4 xv = xr4[j4];
        float4 v1 = W1[j4], v2 = W2[j4], v3 = W3[j4];
        a1 += (double)xv.x * (double)v1.x; a2 += (double)xv.x * (double)v2.x; a3 += (double)xv.x * (double)v3.x;
        a1 += (double)xv.y * (double)v1.y; a2 += (double)xv.y * (double)v2.y; a3 += (double)xv.y * (double)v3.y;
        a1 += (double)xv.z * (double)v1.z; a2 += (double)xv.z * (double)v2.z; a3 += (double)xv.z * (double)v3.z;
        a1 += (double)xv.w * (double)v1.w; a2 += (double)xv.w * (double)v2.w; a3 += (double)xv.w * (double)v3.w;
    }
    if (lane < 3) {
        int j = 1440 + lane;
        double xv = (double)xr[j];
        a1 += xv * (double)wsh[j];
        a2 += xv * (double)wsh[WSTRIDE + j];
        a3 += xv * (double)wsh[2 * WSTRIDE + j];
    }
    for (int off = 32; off > 0; off >>= 1) {
        a1 += __shfl_down(a1, off);
        a2 += __shfl_down(a2, off);
        a3 += __shfl_down(a3, off);
    }
    if (lane == 0) {
        d2[row] = (float)a2;
        d3[row] = (float)a3;
        float invN = ((const float*)st)[8];
        float s = tanhf((float)a1 * invN);
        sv[row] = s;
        keys[row] = fkey(s);
    }
}

// suffix-pick over a 2048-bin LDS histogram. 1024 threads, 2 bins each.
__device__ __forceinline__ void pick2048(
    unsigned* h, unsigned* scan, unsigned kRem,
    unsigned* selS, unsigned* needS, unsigned* hselS)
{
    int tid = threadIdx.x;
    unsigned h0 = h[2 * tid], h1 = h[2 * tid + 1];
    scan[tid] = h0 + h1;
    __syncthreads();
    for (int off = 1; off < 1024; off <<= 1) {
        unsigned v = scan[tid] + ((tid + off < 1024) ? scan[tid + off] : 0u);
        __syncthreads();
        scan[tid] = v;
        __syncthreads();
    }
    unsigned S  = scan[tid];                         // suffix at bin 2t
    unsigned Sn = (tid < 1023) ? scan[tid + 1] : 0u; // suffix at bin 2t+2
    unsigned sufB = S - h0;                          // suffix at bin 2t+1
    if (S >= kRem && sufB < kRem)  { *selS = 2u * tid;     *needS = kRem - sufB; *hselS = h0; }
    if (sufB >= kRem && Sn < kRem) { *selS = 2u * tid + 1; *needS = kRem - Sn;   *hselS = h1; }
    __syncthreads();
}

// single block: optional fused tie-resolution of the PREVIOUS round, then
// full 3-level (11/11/10-bit) radix select over `keys`.
// level 1 uses 8 per-wave-group sub-hists to avoid hot-bin LDS serialization.
__global__ __launch_bounds__(1024) void fpick_kernel(
    const unsigned* __restrict__ keys, int n, int* __restrict__ st, int k0,
    int doTie,
    const float* __restrict__ tSvIn, const int* __restrict__ tIdxIn,
    const float* __restrict__ tCumIn, int tK,
    int* __restrict__ tIdxOut, float* __restrict__ tCumOut,
    const float* __restrict__ tDNext, unsigned* __restrict__ tKeysOut,
    float* __restrict__ tSvOut, int tWIdx)
{
    __shared__ unsigned h8[8][NB1];     // 64 KB
    __shared__ unsigned scan[1024];
    __shared__ unsigned selS, needS, hselS;
    int tid = threadIdx.x;
    int sub = (tid >> 6) & 7;
    unsigned* h = h8[0];

    // ---- fused tie of previous round (writes tail entries of keys/sv/idx/cum)
    if (doTie) {
        int cnt = st[4]; if (cnt > EQCAP) cnt = EQCAP;
        int need = st[2];
        int base = tK - need;
        for (int e = tid; e < cnt; e += 1024) {
            int pos = st[16 + e];
            int rank = 0;
            for (int e2 = 0; e2 < cnt; e2++) rank += (st[16 + e2] < pos) ? 1 : 0;
            if (rank < need) {
                int row = tIdxIn ? tIdxIn[pos] : pos;
                float c = (tIdxIn ? tCumIn[pos] : 1.0f) * tSvIn[pos];
                tIdxOut[base + rank] = row;
                tCumOut[base + rank] = c;
                float invN = ((const float*)st)[8 + tWIdx];
                float s = tanhf(c * tDNext[row] * invN);
                tSvOut[base + rank] = s;
                tKeysOut[base + rank] = fkey(s);
            }
        }
        __threadfence_block();
        __syncthreads();
    }

    // ---- level 1: build from keys
    for (int i = tid; i < 8 * NB1; i += 1024) ((unsigned*)h8)[i] = 0u;
    __syncthreads();
    for (int i = tid; i < n; i += 1024)
        atomicAdd(&h8[sub][keys[i] >> 21], 1u);
    __syncthreads();
    for (int b = tid; b < NB1; b += 1024) {
        unsigned s = h8[0][b];
        for (int w = 1; w < 8; w++) s += h8[w][b];
        h[b] = s;
    }
    __syncthreads();
    pick2048(h, scan, (unsigned)k0, &selS, &needS, &hselS);
    unsigned s1 = selS, kRem2 = needS;
    __syncthreads();

    // ---- level 2: histogram (key>>10)&0x7FF for keys in level-1 bin
    for (int b = tid; b < NB1; b += 1024) h[b] = 0u;
    __syncthreads();
    for (int i = tid; i < n; i += 1024) {
        unsigned k = keys[i];
        if ((k >> 21) == s1) atomicAdd(&h[(k >> 10) & 0x7FFu], 1u);
    }
    __syncthreads();
    pick2048(h, scan, kRem2, &selS, &needS, &hselS);
    unsigned s2 = selS, kRem3 = needS;
    unsigned pref = (s1 << 11) | s2;   // == key >> 10 of the threshold
    __syncthreads();

    // ---- level 3: histogram key&0x3FF (1024 bins; upper half stays zero)
    for (int b = tid; b < NB1; b += 1024) h[b] = 0u;
    __syncthreads();
    for (int i = tid; i < n; i += 1024) {
        unsigned k = keys[i];
        if ((k >> 10) == pref) atomicAdd(&h[k & 0x3FFu], 1u);
    }
    __syncthreads();
    pick2048(h, scan, kRem3, &selS, &needS, &hselS);
    if (tid == 0) {
        st[1] = (int)((s1 << 21) | (s2 << 10) | selS);
        st[2] = (int)needS;
        st[3] = (int)hselS;
        st[4] = 0;
        st[5] = 0;
    }
}

// compact survivors (key > thr); record boundary ties; FUSED: compute next-round
// score/key for each survivor as it is written (dNext==null on last round).
__global__ __launch_bounds__(256) void compact_kernel(
    const unsigned* __restrict__ keysIn, const float* __restrict__ svIn,
    const int* __restrict__ idxIn, const float* __restrict__ cumIn, int n,
    int* __restrict__ idxOut, float* __restrict__ cumOut,
    int* __restrict__ st,
    const float* __restrict__ dNext, unsigned* __restrict__ keysOut,
    float* __restrict__ svOut, int wIdx)
{
    int gid = blockIdx.x * 256 + threadIdx.x;
    if (gid >= n) return;
    unsigned thr = (unsigned)st[1];
    unsigned key = keysIn[gid];
    if (key > thr) {
        int pos = atomicAdd(&st[5], 1);
        int row = idxIn ? idxIn[gid] : gid;
        float c = (idxIn ? cumIn[gid] : 1.0f) * svIn[gid];
        idxOut[pos] = row;
        cumOut[pos] = c;
        if (dNext) {
            float invN = ((const float*)st)[8 + wIdx];
            float s = tanhf(c * dNext[row] * invN);
            svOut[pos] = s;
            keysOut[pos] = fkey(s);
        }
    } else if (key == thr) {
        int e = atomicAdd(&st[4], 1);
        if (e < EQCAP) st[16 + e] = gid;
    }
}

// standalone tie for the LAST round (no following fpick to fuse into)
__global__ __launch_bounds__(256) void tie_kernel(
    const float* __restrict__ svIn, const int* __restrict__ idxIn,
    const float* __restrict__ cumIn, int k,
    int* __restrict__ idxOut, float* __restrict__ cumOut, int* __restrict__ st)
{
    int cnt = st[4]; if (cnt > EQCAP) cnt = EQCAP;
    int need = st[2];
    int base = k - need;
    for (int e = threadIdx.x; e < cnt; e += 256) {
        int pos = st[16 + e];
        int rank = 0;
        for (int e2 = 0; e2 < cnt; e2++) rank += (st[16 + e2] < pos) ? 1 : 0;
        if (rank < need) {
            idxOut[base + rank] = idxIn ? idxIn[pos] : pos;
            cumOut[base + rank] = (idxIn ? cumIn[pos] : 1.0f) * svIn[pos];
        }
    }
}

#define WS_ROWS 64
// out[c] += (1/K3SEL) * sum_r cum3[r] * x[idx3[r]][c]
__global__ __launch_bounds__(256) void wsum_kernel(
    const float* __restrict__ x, const int* __restrict__ idx3,
    const float* __restrict__ cum3, float* __restrict__ out)
{
    int col = blockIdx.x * 256 + threadIdx.x;
    int r0 = blockIdx.y * WS_ROWS;
    int r1 = r0 + WS_ROWS; if (r1 > K3SEL) r1 = K3SEL;
    float acc = 0.0f;
    for (int r = r0; r < r1; r++) {
        int row = idx3[r];
        float wgt = cum3[r];
        if (col < D_FEAT) acc += wgt * x[(long)row * D_FEAT + col];
    }
    if (col < D_FEAT) atomicAdd(&out[col], acc * (1.0f / (float)K3SEL));
}

extern "C" void kernel_launch(void* const* d_in, const int* in_sizes, int n_in,
                              void* d_out, int out_size, void* d_ws, size_t ws_size,
                              hipStream_t stream) {
    const float* x  = (const float*)d_in[0];
    const float* w1 = (const float*)d_in[3];
    const float* w2 = (const float*)d_in[4];
    const float* w3 = (const float*)d_in[5];
    float* out = (float*)d_out;

    float* ws = (float*)d_ws;
    float*    d2    = ws;                          // 100000
    float*    d3    = ws + 100000;                 // 100000
    unsigned* keysA = (unsigned*)(ws + 200000);    // 100000
    float*    svA   = ws + 300000;                 // 100000
    int*      idx1  = (int*)(ws + 400000);         // 50000
    float*    cum1  = ws + 450000;                 // 50000
    unsigned* keysB = (unsigned*)(ws + 500000);    // 50000
    float*    svB   = ws + 550000;                 // 50000
    int*      idx2  = (int*)(ws + 600000);         // 25000
    float*    cum2  = ws + 625000;                 // 25000
    unsigned* keysC = (unsigned*)(ws + 650000);    // 25000
    float*    svC   = ws + 675000;                 // 25000
    int*      idx3  = (int*)(ws + 700000);         // 12500
    float*    cum3  = ws + 712500;                 // 12500
    int*      st    = (int*)(ws + 725000);         // 16 + EQCAP

    init_kernel<<<dim3(16), dim3(256), 0, stream>>>(w1, w2, w3, st, out, out_size);

    dots_kernel<<<dim3(N0 / 16), dim3(1024), 0, stream>>>(x, w1, w2, w3, d2, d3,
                                                          keysA, svA, st);

    // ---- round 1: n=100000 -> k=50000 (compact also scores round 2 with d2)
    fpick_kernel<<<1, 1024, 0, stream>>>(keysA, N0, st, K1SEL,
        0, nullptr, nullptr, nullptr, 0, nullptr, nullptr, nullptr, nullptr, nullptr, 0);
    compact_kernel<<<dim3((N0 + 255) / 256), dim3(256), 0, stream>>>(
        keysA, svA, nullptr, nullptr, N0, idx1, cum1, st, d2, keysB, svB, 1);

    // ---- round 2: n=50000 -> k=25000 (fpick resolves round-1 ties first)
    fpick_kernel<<<1, 1024, 0, stream>>>(keysB, K1SEL, st, K2SEL,
        1, svA, nullptr, nullptr, K1SEL, idx1, cum1, d2, keysB, svB, 1);
    compact_kernel<<<dim3((K1SEL + 255) / 256), dim3(256), 0, stream>>>(
        keysB, svB, idx1, cum1, K1SEL, idx2, cum2, st, d3, keysC, svC, 2);

    // ---- round 3: n=25000 -> k=12500 (fpick resolves round-2 ties first)
    fpick_kernel<<<1, 1024, 0, stream>>>(keysC, K2SEL, st, K3SEL,
        1, svB, idx1, cum1, K2SEL, idx2, cum2, d3, keysC, svC, 2);
    compact_kernel<<<dim3((K2SEL + 255) / 256), dim3(256), 0, stream>>>(
        keysC, svC, idx2, cum2, K2SEL, idx3, cum3, st, nullptr, nullptr, nullptr, 0);
    tie_kernel<<<1, 256, 0, stream>>>(svC, idx2, cum2, K3SEL, idx3, cum3, st);

    // ---- final mean over 12500 weighted rows
    wsum_kernel<<<dim3((D_FEAT + 255) / 256, (K3SEL + WS_ROWS - 1) / WS_ROWS),
                  dim3(256), 0, stream>>>(x, idx3, cum3, out);
}